// Round 7
// baseline (414.585 us; speedup 1.0000x reference)
//
#include <hip/hip_runtime.h>
#include <hip/hip_bf16.h>
#include <math.h>

#define BDIM 8
#define HH 128
#define WW 128
#define LL (HH*WW)          // 16384
#define CC 192
#define CBh 96
#define HBn 4
#define HDd 24
#define PD 6
#define RTAB 217            // (2*4-1)*(2*16-1) for both branches

typedef unsigned short ushortT;
typedef __bf16 bf16x8 __attribute__((ext_vector_type(8)));
typedef float f32x4 __attribute__((ext_vector_type(4)));

__device__ __forceinline__ float b2f(ushortT u){
  union { float f; unsigned u; } x; x.u = ((unsigned)u) << 16; return x.f;
}
__device__ __forceinline__ ushortT f2b(float f){
  union { float f; unsigned u; } x; x.f = f;
  unsigned r = x.u + 0x7fffu + ((x.u >> 16) & 1u);
  return (ushortT)(r >> 16);
}
__device__ __forceinline__ float lo16(unsigned u){ union { float f; unsigned u; } x; x.u = u << 16; return x.f; }
__device__ __forceinline__ float hi16(unsigned u){ union { float f; unsigned u; } x; x.u = u & 0xffff0000u; return x.f; }
__device__ __forceinline__ unsigned pack2(float a, float b){
  return (unsigned)f2b(a) | ((unsigned)f2b(b) << 16);
}
__device__ __forceinline__ void unpack8(uint4 u, float* f){
  f[0]=lo16(u.x); f[1]=hi16(u.x); f[2]=lo16(u.y); f[3]=hi16(u.y);
  f[4]=lo16(u.z); f[5]=hi16(u.z); f[6]=lo16(u.w); f[7]=hi16(u.w);
}
// v_cvt_pk_bf16_f32 via HIP intrinsic (RNE)
__device__ __forceinline__ unsigned cvt2(float a, float b){
  __hip_bfloat162 h = __float22bfloat162_rn(float2{a, b});
  union { __hip_bfloat162 h; unsigned u; } c; c.h = h; return c.u;
}
__device__ __forceinline__ float gelu_exact(float x){
  return 0.5f * x * (1.0f + erff(x * 0.70710678118654752f));
}

union ABu { unsigned u[4]; bf16x8 v; };

// ---- per-k-step B tile staging: [192 rows][32 k] bf16 = 12288 B, dbuf ----
// LDS row stride 64 B -> wave b128 reads (row*64 + hk*16) hit all 32 banks
// evenly (lr*16 mod 32 in {0,16}; +hk*4 covers the rest): conflict-free.
#define BTILE 12288

__device__ __forceinline__ void stageB(const ushortT* __restrict__ W, int ks, char* lds){
  for (int c = threadIdx.x; c < 768; c += 512){
    int n = c >> 2, kc = c & 3;
    uint4 v = *(const uint4*)(const void*)(W + n*CC + ks*32 + kc*8);
    *(uint4*)(lds + n*64 + kc*16) = v;
  }
}

// ---------------- K0: dynamic position-bias MLP -> pos[2][217][4] ----------------
__device__ __forceinline__ void ln_relu6(float* p, const float* g, const float* b){
  float m = 0.f;
  #pragma unroll
  for (int j=0;j<PD;j++) m += p[j];
  m *= (1.0f/PD);
  float v = 0.f;
  #pragma unroll
  for (int j=0;j<PD;j++){ float d = p[j]-m; v += d*d; }
  v *= (1.0f/PD);
  float is = rsqrtf(v + 1e-5f);
  #pragma unroll
  for (int j=0;j<PD;j++){ float t = (p[j]-m)*is*g[j] + b[j]; p[j] = t > 0.f ? t : 0.f; }
}
__device__ __forceinline__ void mm6(float* p, const float* w, const float* c){
  float q[PD];
  #pragma unroll
  for (int j=0;j<PD;j++){
    float a = c[j];
    #pragma unroll
    for (int i=0;i<PD;i++) a += p[i]*w[j*PD+i];
    q[j] = a;
  }
  #pragma unroll
  for (int j=0;j<PD;j++) p[j] = q[j];
}

__global__ void k_pos(const float* __restrict__ pw, const float* __restrict__ pb,
                      const float* __restrict__ g1, const float* __restrict__ b1,
                      const float* __restrict__ w1, const float* __restrict__ c1,
                      const float* __restrict__ g2, const float* __restrict__ b2,
                      const float* __restrict__ w2, const float* __restrict__ c2,
                      const float* __restrict__ g3, const float* __restrict__ b3,
                      const float* __restrict__ w3, const float* __restrict__ c3,
                      float* __restrict__ pos){
  int br = blockIdx.x;
  int r = threadIdx.x;
  if (r >= RTAB) return;
  int Hsp = br ? 16 : 4, Wsp = br ? 4 : 16;
  int W2 = 2*Wsp - 1;
  float bi0 = (float)(r / W2 - (Hsp-1));
  float bi1 = (float)(r % W2 - (Wsp-1));
  const float* PW = pw + br*PD*2;
  const float* PB = pb + br*PD;
  float p[PD];
  #pragma unroll
  for (int j=0;j<PD;j++) p[j] = PW[j*2]*bi0 + PW[j*2+1]*bi1 + PB[j];
  ln_relu6(p, g1+br*PD, b1+br*PD);
  mm6(p, w1+br*PD*PD, c1+br*PD);
  ln_relu6(p, g2+br*PD, b2+br*PD);
  mm6(p, w2+br*PD*PD, c2+br*PD);
  ln_relu6(p, g3+br*PD, b3+br*PD);
  const float* W3 = w3 + br*HBn*PD;
  const float* C3 = c3 + br*HBn;
  #pragma unroll
  for (int h=0;h<HBn;h++){
    float a = C3[h];
    #pragma unroll
    for (int i=0;i<PD;i++) a += p[i]*W3[h*PD+i];
    pos[((size_t)br*RTAB + r)*HBn + h] = a;
  }
}

// ---------------- K-cvt: convert weights to bf16; fold BN params; build conv tables ----------------
#define WQKV_ELEMS (3*CC*CC)                     // 110592
#define WPROJ_ELEMS (CC*CC)                      // 36864
#define WSI_ELEMS (CC*CBh)                       // 18432
#define WALL_PAIRS ((WQKV_ELEMS+WPROJ_ELEMS+WSI_ELEMS)/2)  // 82944

__global__ void k_cvtw(const float* __restrict__ qkv_w, const float* __restrict__ proj_w,
                       const float* __restrict__ si_w1,
                       const float* __restrict__ si_b1,
                       const float* __restrict__ g, const float* __restrict__ bb,
                       const float* __restrict__ mn, const float* __restrict__ vv,
                       const float* __restrict__ si_w2,
                       const float* __restrict__ dw_w, const float* __restrict__ dw_b,
                       const float* __restrict__ bn1_g, const float* __restrict__ bn1_b,
                       const float* __restrict__ bn1_m, const float* __restrict__ bn1_v,
                       ushortT* __restrict__ wb, float* __restrict__ gparam,
                       float* __restrict__ cparam, ushortT* __restrict__ dwt){
  int t = threadIdx.x;
  if (blockIdx.x == 0 && t < CBh){
    float sc = g[t]*rsqrtf(vv[t]+1e-5f);
    gparam[t]        = sc;                                   // scale
    gparam[CBh+t]    = (si_b1[t]-mn[t])*sc + bb[t];          // folded bias
    gparam[2*CBh+t]  = si_w2[t];                             // w2
  }
  if (blockIdx.x == 1){
    if (t < CC){
      float sc = bn1_g[t]*rsqrtf(bn1_v[t]+1e-5f);
      cparam[t]      = sc;
      cparam[CC+t]   = (dw_b[t]-bn1_m[t])*sc + bn1_b[t];
    }
    for (int i = t; i < 9*CC; i += 256){
      int k = i / CC, c = i - k*CC;
      dwt[i] = f2b(dw_w[c*9 + k]);
    }
  }
  int i = blockIdx.x*256 + t;
  if (i >= WALL_PAIRS) return;
  int e = i*2;
  float a, b;
  if (e < WQKV_ELEMS){ a = qkv_w[e]; b = qkv_w[e+1]; }
  else if (e < WQKV_ELEMS+WPROJ_ELEMS){ a = proj_w[e-WQKV_ELEMS]; b = proj_w[e-WQKV_ELEMS+1]; }
  else { a = si_w1[e-WQKV_ELEMS-WPROJ_ELEMS]; b = si_w1[e-WQKV_ELEMS-WPROJ_ELEMS+1]; }
  *(unsigned*)(void*)(wb + e) = cvt2(a, b);
}

// ---------------- K1: QKV GEMM via MFMA, B k-tile double-buffered in LDS ----------------
// Block 512 thr = 8 waves; block covers 256 rows; wave = 32 rows x 192 cols.
__global__ __launch_bounds__(512) void k_qkv(const float* __restrict__ x1, const float* __restrict__ x2,
                                             const ushortT* __restrict__ wb,
                                             ushortT* __restrict__ q1, ushortT* __restrict__ k2,
                                             ushortT* __restrict__ v1){
  __shared__ char Bs[2][BTILE];    // 24576 B
  int z = blockIdx.y;
  const float* src = (z == 1) ? x2 : x1;
  ushortT* dst = (z == 0) ? q1 : ((z == 1) ? k2 : v1);
  const ushortT* W = wb + (size_t)z*CC*CC;
  stageB(W, 0, Bs[0]);

  int w = threadIdx.x >> 6, l = threadIdx.x & 63;
  int row0 = blockIdx.x*256 + w*32;
  int lr = l & 15;            // frag row (A) / col (B)
  int hk = l >> 4;            // k-phase
  f32x4 acc[2][12];
  #pragma unroll
  for (int rt=0; rt<2; rt++)
    #pragma unroll
    for (int n=0; n<12; n++) acc[rt][n] = (f32x4){0.f,0.f,0.f,0.f};

  const float* ap0 = src + (size_t)(row0 + lr)*CC + hk*8;
  const float* ap1 = ap0 + (size_t)16*CC;
  float4 pA00 = *(const float4*)(ap0);
  float4 pA01 = *(const float4*)(ap0 + 4);
  float4 pA10 = *(const float4*)(ap1);
  float4 pA11 = *(const float4*)(ap1 + 4);
  __syncthreads();

  #pragma unroll
  for (int ks = 0; ks < 6; ks++){
    int cur = ks & 1;
    float4 nA00, nA01, nA10, nA11;
    if (ks < 5){
      const float* np0 = ap0 + (ks+1)*32;
      const float* np1 = ap1 + (ks+1)*32;
      nA00 = *(const float4*)(np0);
      nA01 = *(const float4*)(np0 + 4);
      nA10 = *(const float4*)(np1);
      nA11 = *(const float4*)(np1 + 4);
      stageB(W, ks+1, Bs[cur^1]);
    }
    ABu a0, a1;
    a0.u[0] = cvt2(pA00.x, pA00.y); a0.u[1] = cvt2(pA00.z, pA00.w);
    a0.u[2] = cvt2(pA01.x, pA01.y); a0.u[3] = cvt2(pA01.z, pA01.w);
    a1.u[0] = cvt2(pA10.x, pA10.y); a1.u[1] = cvt2(pA10.z, pA10.w);
    a1.u[2] = cvt2(pA11.x, pA11.y); a1.u[3] = cvt2(pA11.z, pA11.w);
    #pragma unroll
    for (int n=0; n<12; n++){
      bf16x8 bfr = *(const bf16x8*)(Bs[cur] + (n*16 + lr)*64 + hk*16);
      acc[0][n] = __builtin_amdgcn_mfma_f32_16x16x32_bf16(a0.v, bfr, acc[0][n], 0, 0, 0);
      acc[1][n] = __builtin_amdgcn_mfma_f32_16x16x32_bf16(a1.v, bfr, acc[1][n], 0, 0, 0);
    }
    if (ks < 5){
      pA00 = nA00; pA01 = nA01; pA10 = nA10; pA11 = nA11;
    }
    __syncthreads();
  }
  int crow = hk*4, ccol = lr;
  #pragma unroll
  for (int rt=0; rt<2; rt++)
    #pragma unroll
    for (int n=0; n<12; n++)
      #pragma unroll
      for (int r=0; r<4; r++){
        int m = row0 + rt*16 + crow + r;
        dst[(size_t)m*CC + n*16 + ccol] = f2b(acc[rt][n][r]);
      }
}

// ---------------- K2: windowed attention (one branch per template) ----------------
template<int HSP, int WSP>
__global__ __launch_bounds__(256) void k_attn(const ushortT* __restrict__ q1, const ushortT* __restrict__ k2,
                                              const ushortT* __restrict__ v1, const float* __restrict__ pos,
                                              ushortT* __restrict__ att){
  constexpr int BR = (HSP == 4) ? 0 : 1;
  constexpr int NWH = HH / HSP, NWW = WW / WSP;
  constexpr int CH0 = BR * CBh;
  __shared__ float ks[64][CBh];
  __shared__ float vs[64][CBh];
  __shared__ float ps[RTAB*HBn];
  int t = threadIdx.x;
  int wid = blockIdx.x;
  int b = wid / (NWH*NWW);
  int rem = wid - b*(NWH*NWW);
  int hi = rem / NWW, wj = rem - hi*NWW;
  for (int i = t; i < RTAB*HBn; i += 256) ps[i] = pos[(size_t)BR*RTAB*HBn + i];
  #pragma unroll
  for (int r = 0; r < 3; r++){
    int idx = t + r*256;        // < 768 = 64 pix * 12 segs
    int pix = idx / 12, seg = idx - pix*12;
    int ii = pix / WSP, jj = pix - ii*WSP;
    size_t base = (((size_t)b*LL) + (size_t)(hi*HSP+ii)*WW + wj*WSP + jj)*CC + CH0 + seg*8;
    uint4 uk = *(const uint4*)(const void*)(k2 + base);
    unpack8(uk, &ks[pix][seg*8]);
    uint4 uv = *(const uint4*)(const void*)(v1 + base);
    unpack8(uv, &vs[pix][seg*8]);
  }
  __syncthreads();
  int h = t >> 6, lane = t & 63;
  int i1 = lane / WSP, j1 = lane - i1*WSP;
  size_t lq = ((size_t)b*LL) + (size_t)(hi*HSP+i1)*WW + wj*WSP + j1;
  const ushortT* qrow = q1 + lq*CC + CH0 + h*HDd;
  float qf[HDd];
  #pragma unroll
  for (int d0 = 0; d0 < HDd; d0 += 8){
    uint4 u = *(const uint4*)(const void*)(qrow + d0);
    unpack8(u, &qf[d0]);
  }
  #pragma unroll
  for (int d=0; d<HDd; d++) qf[d] *= 0.20412414523193154f;   // 1/sqrt(24)
  float lg[64];
  #pragma unroll
  for (int m = 0; m < 64; m++){
    const float* kr = &ks[m][h*HDd];
    float s = 0.f;
    #pragma unroll
    for (int d=0; d<HDd; d++) s = fmaf(qf[d], kr[d], s);
    int i2 = m / WSP, j2 = m - i2*WSP;
    int ridx = (i1-i2+HSP-1)*(2*WSP-1) + (j1-j2+WSP-1);
    lg[m] = s + ps[ridx*HBn + h];
  }
  float mx = lg[0];
  #pragma unroll
  for (int m=1;m<64;m++) mx = fmaxf(mx, lg[m]);
  float sum = 0.f;
  #pragma unroll
  for (int m=0;m<64;m++){ lg[m] = __expf(lg[m]-mx); sum += lg[m]; }
  float inv = 1.0f / sum;
  float z[HDd];
  #pragma unroll
  for (int d=0;d<HDd;d++) z[d] = 0.f;
  #pragma unroll
  for (int m=0;m<64;m++){
    float p = lg[m]*inv;
    const float* vr = &vs[m][h*HDd];
    #pragma unroll
    for (int d=0;d<HDd;d++) z[d] = fmaf(p, vr[d], z[d]);
  }
  ushortT* orow = att + lq*CC + CH0 + h*HDd;
  #pragma unroll
  for (int d0=0; d0<HDd; d0+=8){
    uint4 u;
    u.x = pack2(z[d0+0], z[d0+1]);
    u.y = pack2(z[d0+2], z[d0+3]);
    u.z = pack2(z[d0+4], z[d0+5]);
    u.w = pack2(z[d0+6], z[d0+7]);
    *(uint4*)(void*)(orow + d0) = u;
  }
}

// ---------------- K3: depthwise 3x3 conv + BN + GELU, 8 channels/thread ----------------
__global__ __launch_bounds__(256) void k_conv(const ushortT* __restrict__ v1,
                                              const ushortT* __restrict__ dwt,
                                              const float* __restrict__ cparam,
                                              ushortT* __restrict__ cx){
  int tid = blockIdx.x*256 + threadIdx.x;     // SZ/8 total
  int grp = tid % 24;
  int pix = tid / 24;
  int j = pix & (WW-1);
  int rest = pix >> 7;
  int i = rest & (HH-1);
  int b = rest >> 7;
  int c0 = grp*8;
  uint4 wreg[9];
  #pragma unroll
  for (int k=0;k<9;k++) wreg[k] = *(const uint4*)(const void*)(dwt + k*CC + c0);
  float acc[8];
  #pragma unroll
  for (int t2=0;t2<8;t2++) acc[t2]=0.f;
  #pragma unroll
  for (int ki=0;ki<3;ki++){
    int ii = i + ki - 1;
    if (ii < 0 || ii >= HH) continue;
    #pragma unroll
    for (int kj=0;kj<3;kj++){
      int jj = j + kj - 1;
      if (jj < 0 || jj >= WW) continue;
      uint4 uv = *(const uint4*)(const void*)(v1 + (((size_t)b*LL) + (size_t)ii*WW + jj)*CC + c0);
      float fv[8], fw[8];
      unpack8(uv, fv);
      unpack8(wreg[ki*3+kj], fw);
      #pragma unroll
      for (int t2=0;t2<8;t2++) acc[t2] = fmaf(fv[t2], fw[t2], acc[t2]);
    }
  }
  float4 s0 = *(const float4*)(cparam + c0);
  float4 s1 = *(const float4*)(cparam + c0 + 4);
  float4 o0 = *(const float4*)(cparam + CC + c0);
  float4 o1 = *(const float4*)(cparam + CC + c0 + 4);
  float scv[8] = {s0.x,s0.y,s0.z,s0.w,s1.x,s1.y,s1.z,s1.w};
  float ofv[8] = {o0.x,o0.y,o0.z,o0.w,o1.x,o1.y,o1.z,o1.w};
  unsigned ou[4];
  #pragma unroll
  for (int t2=0;t2<4;t2++){
    float y0 = gelu_exact(acc[2*t2]  *scv[2*t2]   + ofv[2*t2]);
    float y1 = gelu_exact(acc[2*t2+1]*scv[2*t2+1] + ofv[2*t2+1]);
    ou[t2] = pack2(y0, y1);
  }
  uint4 res; res.x=ou[0]; res.y=ou[1]; res.z=ou[2]; res.w=ou[3];
  *(uint4*)(void*)(cx + (size_t)pix*CC + c0) = res;
}

// ---------------- K4: per-pixel SE gate via MFMA ----------------
__global__ __launch_bounds__(256) void k_gate(const ushortT* __restrict__ att,
                                              const ushortT* __restrict__ wsi,
                                              const float* __restrict__ gparam,
                                              const float* __restrict__ si_b2,
                                              float* __restrict__ gate){
  int w = threadIdx.x >> 6, l = threadIdx.x & 63;
  int row0 = blockIdx.x*128 + w*32;
  int lr = l & 15;
  int lk = (l >> 4) * 8;
  f32x4 acc[2][6];
  #pragma unroll
  for (int rt=0; rt<2; rt++)
    #pragma unroll
    for (int n=0; n<6; n++) acc[rt][n] = (f32x4){0.f,0.f,0.f,0.f};
  #pragma unroll
  for (int ks = 0; ks < 6; ks++){
    int k0 = ks*32 + lk;
    bf16x8 a0 = *(const bf16x8*)(const void*)(att + (size_t)(row0 + lr)*CC + k0);
    bf16x8 a1 = *(const bf16x8*)(const void*)(att + (size_t)(row0 + 16 + lr)*CC + k0);
    #pragma unroll
    for (int n=0; n<6; n++){
      bf16x8 bfr = *(const bf16x8*)(const void*)(wsi + (size_t)(n*16 + lr)*CC + k0);
      acc[0][n] = __builtin_amdgcn_mfma_f32_16x16x32_bf16(a0, bfr, acc[0][n], 0, 0, 0);
      acc[1][n] = __builtin_amdgcn_mfma_f32_16x16x32_bf16(a1, bfr, acc[1][n], 0, 0, 0);
    }
  }
  int crow = (l >> 4) * 4, ccol = l & 15;
  float sc6[6], cb6[6], w26[6];
  #pragma unroll
  for (int n=0; n<6; n++){
    int o = n*16 + ccol;
    sc6[n] = gparam[o];
    cb6[n] = gparam[CBh + o];
    w26[n] = gparam[2*CBh + o];
  }
  float sb2 = si_b2[0];
  float ps[2][4];
  #pragma unroll
  for (int rt=0; rt<2; rt++)
    #pragma unroll
    for (int r=0; r<4; r++) ps[rt][r] = 0.f;
  #pragma unroll
  for (int rt=0; rt<2; rt++)
    #pragma unroll
    for (int n=0; n<6; n++)
      #pragma unroll
      for (int r=0; r<4; r++){
        float x = acc[rt][n][r]*sc6[n] + cb6[n];
        ps[rt][r] += gelu_exact(x) * w26[n];
      }
  #pragma unroll
  for (int rt=0; rt<2; rt++)
    #pragma unroll
    for (int r=0; r<4; r++){
      float v = ps[rt][r];
      #pragma unroll
      for (int off = 1; off < 16; off <<= 1) v += __shfl_xor(v, off, 64);
      ps[rt][r] = v;
    }
  if (ccol == 0){
    #pragma unroll
    for (int rt=0; rt<2; rt++)
      #pragma unroll
      for (int r=0; r<4; r++){
        int m = row0 + rt*16 + crow + r;
        gate[m] = 1.0f / (1.0f + __expf(-(ps[rt][r] + sb2)));
      }
  }
}

// ---------------- K5: proj GEMM via MFMA, B k-tile dbuf in LDS, fused A = att + gate*convx ----------------
__global__ __launch_bounds__(512) void k_proj(const ushortT* __restrict__ att, const ushortT* __restrict__ cx,
                                              const float* __restrict__ gate,
                                              const ushortT* __restrict__ wp, const float* __restrict__ pbias,
                                              float* __restrict__ out){
  __shared__ char Bs[2][BTILE];    // 24576 B
  stageB(wp, 0, Bs[0]);

  int w = threadIdx.x >> 6, l = threadIdx.x & 63;
  int row0 = blockIdx.x*256 + w*32;
  int lr = l & 15;
  int hk = l >> 4;
  float gv0 = gate[row0 + lr];
  float gv1 = gate[row0 + 16 + lr];
  f32x4 acc[2][12];
  #pragma unroll
  for (int rt=0; rt<2; rt++)
    #pragma unroll
    for (int n=0; n<12; n++) acc[rt][n] = (f32x4){0.f,0.f,0.f,0.f};

  size_t base0 = (size_t)(row0 + lr)*CC + hk*8;
  size_t base1 = base0 + (size_t)16*CC;
  uint4 pa0 = *(const uint4*)(const void*)(att + base0);
  uint4 pc0 = *(const uint4*)(const void*)(cx + base0);
  uint4 pa1 = *(const uint4*)(const void*)(att + base1);
  uint4 pc1 = *(const uint4*)(const void*)(cx + base1);
  __syncthreads();

  #pragma unroll
  for (int ks = 0; ks < 6; ks++){
    int cur = ks & 1;
    uint4 na0, nc0, na1, nc1;
    if (ks < 5){
      na0 = *(const uint4*)(const void*)(att + base0 + (ks+1)*32);
      nc0 = *(const uint4*)(const void*)(cx  + base0 + (ks+1)*32);
      na1 = *(const uint4*)(const void*)(att + base1 + (ks+1)*32);
      nc1 = *(const uint4*)(const void*)(cx  + base1 + (ks+1)*32);
      stageB(wp, ks+1, Bs[cur^1]);
    }
    float fa[8], fc[8], fb[8], fd[8];
    unpack8(pa0, fa); unpack8(pc0, fc);
    unpack8(pa1, fb); unpack8(pc1, fd);
    #pragma unroll
    for (int j=0;j<8;j++){ fa[j] = fmaf(gv0, fc[j], fa[j]); fb[j] = fmaf(gv1, fd[j], fb[j]); }
    ABu a0, a1;
    a0.u[0] = cvt2(fa[0], fa[1]); a0.u[1] = cvt2(fa[2], fa[3]);
    a0.u[2] = cvt2(fa[4], fa[5]); a0.u[3] = cvt2(fa[6], fa[7]);
    a1.u[0] = cvt2(fb[0], fb[1]); a1.u[1] = cvt2(fb[2], fb[3]);
    a1.u[2] = cvt2(fb[4], fb[5]); a1.u[3] = cvt2(fb[6], fb[7]);
    #pragma unroll
    for (int n=0; n<12; n++){
      bf16x8 bfr = *(const bf16x8*)(Bs[cur] + (n*16 + lr)*64 + hk*16);
      acc[0][n] = __builtin_amdgcn_mfma_f32_16x16x32_bf16(a0.v, bfr, acc[0][n], 0, 0, 0);
      acc[1][n] = __builtin_amdgcn_mfma_f32_16x16x32_bf16(a1.v, bfr, acc[1][n], 0, 0, 0);
    }
    if (ks < 5){
      pa0 = na0; pc0 = nc0; pa1 = na1; pc1 = nc1;
    }
    __syncthreads();
  }
  int crow = hk*4, ccol = lr;
  #pragma unroll
  for (int n=0; n<12; n++){
    float bv = pbias[n*16 + ccol];
    #pragma unroll
    for (int rt=0; rt<2; rt++)
      #pragma unroll
      for (int r=0; r<4; r++){
        int m = row0 + rt*16 + crow + r;
        out[(size_t)m*CC + n*16 + ccol] = acc[rt][n][r] + bv;
      }
  }
}

extern "C" void kernel_launch(void* const* d_in, const int* in_sizes, int n_in,
                              void* d_out, int out_size, void* d_ws, size_t ws_size,
                              hipStream_t stream){
  const float* x1    = (const float*)d_in[0];
  const float* x2    = (const float*)d_in[1];
  const float* qkv_w = (const float*)d_in[2];
  const float* proj_w= (const float*)d_in[3];
  const float* proj_b= (const float*)d_in[4];
  const float* pw    = (const float*)d_in[5];
  const float* pb    = (const float*)d_in[6];
  const float* g1    = (const float*)d_in[7];
  const float* b1    = (const float*)d_in[8];
  const float* w1    = (const float*)d_in[9];
  const float* c1    = (const float*)d_in[10];
  const float* g2    = (const float*)d_in[11];
  const float* b2    = (const float*)d_in[12];
  const float* w2    = (const float*)d_in[13];
  const float* c2    = (const float*)d_in[14];
  const float* g3    = (const float*)d_in[15];
  const float* b3    = (const float*)d_in[16];
  const float* w3    = (const float*)d_in[17];
  const float* c3    = (const float*)d_in[18];
  const float* dw_w  = (const float*)d_in[19];
  const float* dw_b  = (const float*)d_in[20];
  const float* bn1_g = (const float*)d_in[21];
  const float* bn1_b = (const float*)d_in[22];
  const float* bn1_m = (const float*)d_in[23];
  const float* bn1_v = (const float*)d_in[24];
  const float* si_w1 = (const float*)d_in[25];
  const float* si_b1 = (const float*)d_in[26];
  const float* bn2_g = (const float*)d_in[27];
  const float* bn2_b = (const float*)d_in[28];
  const float* bn2_m = (const float*)d_in[29];
  const float* bn2_v = (const float*)d_in[30];
  const float* si_w2 = (const float*)d_in[31];
  const float* si_b2 = (const float*)d_in[32];
  float* out = (float*)d_out;

  char* ws = (char*)d_ws;
  const size_t SZ  = (size_t)BDIM * LL * CC;   // 25,165,824 elements
  const size_t SZB = SZ * 2;                   // bf16 bytes per buffer
  ushortT* q1   = (ushortT*)(ws);
  ushortT* v1   = (ushortT*)(ws + SZB);
  ushortT* k2   = (ushortT*)(ws + 2*SZB);
  ushortT* att  = (ushortT*)(ws + 3*SZB);
  float*   gate = (float*)  (ws + 4*SZB);
  float*   pos  = (float*)  (ws + 4*SZB + (size_t)BDIM*LL*sizeof(float));
  ushortT* wbf  = (ushortT*)(ws + 4*SZB + (size_t)BDIM*LL*sizeof(float) + 16384);
  ushortT* wproj = wbf + WQKV_ELEMS;
  ushortT* wsi   = wproj + WPROJ_ELEMS;
  float*   gparam = (float*)(wbf + WQKV_ELEMS + WPROJ_ELEMS + WSI_ELEMS);
  float*   cparam = gparam + 3*CBh;
  ushortT* dwt    = (ushortT*)(cparam + 2*CC);
  ushortT* convx = q1;   // q1 dead after attention

  k_pos<<<dim3(2), dim3(256), 0, stream>>>(pw,pb,g1,b1,w1,c1,g2,b2,w2,c2,g3,b3,w3,c3,pos);
  k_cvtw<<<dim3((WALL_PAIRS+255)/256), dim3(256), 0, stream>>>(qkv_w, proj_w, si_w1,
      si_b1, bn2_g, bn2_b, bn2_m, bn2_v, si_w2,
      dw_w, dw_b, bn1_g, bn1_b, bn1_m, bn1_v, wbf, gparam, cparam, dwt);
  k_qkv<<<dim3(512,3), dim3(512), 0, stream>>>(x1, x2, wbf, q1, k2, v1);
  k_attn<4,16><<<dim3(2048), dim3(256), 0, stream>>>(q1, k2, v1, pos, att);
  k_attn<16,4><<<dim3(2048), dim3(256), 0, stream>>>(q1, k2, v1, pos, att);
  k_conv<<<dim3((unsigned)(SZ/8/256)), dim3(256), 0, stream>>>(v1, dwt, cparam, convx);
  k_gate<<<dim3(1024), dim3(256), 0, stream>>>(att, wsi, gparam, si_b2, gate);
  k_proj<<<dim3(512), dim3(512), 0, stream>>>(att, convx, gate, wproj, proj_b, out);
}

// Round 8
// 389.524 us; speedup vs baseline: 1.0643x; 1.0643x over previous
//
#include <hip/hip_runtime.h>
#include <hip/hip_bf16.h>
#include <math.h>

#define BDIM 8
#define HH 128
#define WW 128
#define LL (HH*WW)          // 16384
#define CC 192
#define CBh 96
#define HBn 4
#define HDd 24
#define PD 6
#define RTAB 217            // (2*4-1)*(2*16-1) for both branches

typedef unsigned short ushortT;
typedef __bf16 bf16x8 __attribute__((ext_vector_type(8)));
typedef float f32x4 __attribute__((ext_vector_type(4)));

__device__ __forceinline__ float b2f(ushortT u){
  union { float f; unsigned u; } x; x.u = ((unsigned)u) << 16; return x.f;
}
__device__ __forceinline__ ushortT f2b(float f){
  union { float f; unsigned u; } x; x.f = f;
  unsigned r = x.u + 0x7fffu + ((x.u >> 16) & 1u);
  return (ushortT)(r >> 16);
}
__device__ __forceinline__ float lo16(unsigned u){ union { float f; unsigned u; } x; x.u = u << 16; return x.f; }
__device__ __forceinline__ float hi16(unsigned u){ union { float f; unsigned u; } x; x.u = u & 0xffff0000u; return x.f; }
__device__ __forceinline__ unsigned pack2(float a, float b){
  return (unsigned)f2b(a) | ((unsigned)f2b(b) << 16);
}
__device__ __forceinline__ void unpack8(uint4 u, float* f){
  f[0]=lo16(u.x); f[1]=hi16(u.x); f[2]=lo16(u.y); f[3]=hi16(u.y);
  f[4]=lo16(u.z); f[5]=hi16(u.z); f[6]=lo16(u.w); f[7]=hi16(u.w);
}
// v_cvt_pk_bf16_f32 via HIP intrinsic (RNE)
__device__ __forceinline__ unsigned cvt2(float a, float b){
  __hip_bfloat162 h = __float22bfloat162_rn(float2{a, b});
  union { __hip_bfloat162 h; unsigned u; } c; c.h = h; return c.u;
}
__device__ __forceinline__ float gelu_exact(float x){
  return 0.5f * x * (1.0f + erff(x * 0.70710678118654752f));
}

union ABu { unsigned u[4]; bf16x8 v; };

// ---- LDS weight staging: full 192x192 bf16 slice (73728 B), XOR-swizzled ----
// byte ^= ((row&7)<<4): consecutive lanes hit consecutive 16B slots (measured
// 0 conflicts in r6; the 64B-stride variant measured 3.5M — keep THIS layout).
__device__ __forceinline__ void stage_B512(const ushortT* __restrict__ Wsrc, char* lds){
  int t = threadIdx.x;
  #pragma unroll
  for (int i = 0; i < 9; i++){
    int c = t + i*512;                 // 16B-chunk index, 4608 total
    int n = c / 24, kc = c - n*24;     // row, chunk-in-row
    uint4 v = *(const uint4*)(const void*)(Wsrc + n*CC + kc*8);
    int byte = n*384 + kc*16;
    byte ^= ((n & 7) << 4);
    *(uint4*)(lds + byte) = v;
  }
}
__device__ __forceinline__ bf16x8 ldsB(const char* lds, int row, int kbyte){
  int byte = row*384 + kbyte;
  byte ^= ((row & 7) << 4);
  return *(const bf16x8*)(lds + byte);
}

// ---------------- K0: dynamic position-bias MLP -> pos[2][217][4] ----------------
__device__ __forceinline__ void ln_relu6(float* p, const float* g, const float* b){
  float m = 0.f;
  #pragma unroll
  for (int j=0;j<PD;j++) m += p[j];
  m *= (1.0f/PD);
  float v = 0.f;
  #pragma unroll
  for (int j=0;j<PD;j++){ float d = p[j]-m; v += d*d; }
  v *= (1.0f/PD);
  float is = rsqrtf(v + 1e-5f);
  #pragma unroll
  for (int j=0;j<PD;j++){ float t = (p[j]-m)*is*g[j] + b[j]; p[j] = t > 0.f ? t : 0.f; }
}
__device__ __forceinline__ void mm6(float* p, const float* w, const float* c){
  float q[PD];
  #pragma unroll
  for (int j=0;j<PD;j++){
    float a = c[j];
    #pragma unroll
    for (int i=0;i<PD;i++) a += p[i]*w[j*PD+i];
    q[j] = a;
  }
  #pragma unroll
  for (int j=0;j<PD;j++) p[j] = q[j];
}

__global__ void k_pos(const float* __restrict__ pw, const float* __restrict__ pb,
                      const float* __restrict__ g1, const float* __restrict__ b1,
                      const float* __restrict__ w1, const float* __restrict__ c1,
                      const float* __restrict__ g2, const float* __restrict__ b2,
                      const float* __restrict__ w2, const float* __restrict__ c2,
                      const float* __restrict__ g3, const float* __restrict__ b3,
                      const float* __restrict__ w3, const float* __restrict__ c3,
                      float* __restrict__ pos){
  int br = blockIdx.x;
  int r = threadIdx.x;
  if (r >= RTAB) return;
  int Hsp = br ? 16 : 4, Wsp = br ? 4 : 16;
  int W2 = 2*Wsp - 1;
  float bi0 = (float)(r / W2 - (Hsp-1));
  float bi1 = (float)(r % W2 - (Wsp-1));
  const float* PW = pw + br*PD*2;
  const float* PB = pb + br*PD;
  float p[PD];
  #pragma unroll
  for (int j=0;j<PD;j++) p[j] = PW[j*2]*bi0 + PW[j*2+1]*bi1 + PB[j];
  ln_relu6(p, g1+br*PD, b1+br*PD);
  mm6(p, w1+br*PD*PD, c1+br*PD);
  ln_relu6(p, g2+br*PD, b2+br*PD);
  mm6(p, w2+br*PD*PD, c2+br*PD);
  ln_relu6(p, g3+br*PD, b3+br*PD);
  const float* W3 = w3 + br*HBn*PD;
  const float* C3 = c3 + br*HBn;
  #pragma unroll
  for (int h=0;h<HBn;h++){
    float a = C3[h];
    #pragma unroll
    for (int i=0;i<PD;i++) a += p[i]*W3[h*PD+i];
    pos[((size_t)br*RTAB + r)*HBn + h] = a;
  }
}

// ---------------- K-cvt: convert weights to bf16; fold BN params; build conv tables ----------------
#define WQKV_ELEMS (3*CC*CC)                     // 110592
#define WPROJ_ELEMS (CC*CC)                      // 36864
#define WSI_ELEMS (CC*CBh)                       // 18432
#define WALL_PAIRS ((WQKV_ELEMS+WPROJ_ELEMS+WSI_ELEMS)/2)  // 82944

__global__ void k_cvtw(const float* __restrict__ qkv_w, const float* __restrict__ proj_w,
                       const float* __restrict__ si_w1,
                       const float* __restrict__ si_b1,
                       const float* __restrict__ g, const float* __restrict__ bb,
                       const float* __restrict__ mn, const float* __restrict__ vv,
                       const float* __restrict__ si_w2,
                       const float* __restrict__ dw_w, const float* __restrict__ dw_b,
                       const float* __restrict__ bn1_g, const float* __restrict__ bn1_b,
                       const float* __restrict__ bn1_m, const float* __restrict__ bn1_v,
                       ushortT* __restrict__ wb, float* __restrict__ gparam,
                       float* __restrict__ cparam, ushortT* __restrict__ dwt){
  int t = threadIdx.x;
  if (blockIdx.x == 0 && t < CBh){
    float sc = g[t]*rsqrtf(vv[t]+1e-5f);
    gparam[t]        = sc;                                   // scale
    gparam[CBh+t]    = (si_b1[t]-mn[t])*sc + bb[t];          // folded bias
    gparam[2*CBh+t]  = si_w2[t];                             // w2
  }
  if (blockIdx.x == 1){
    if (t < CC){
      float sc = bn1_g[t]*rsqrtf(bn1_v[t]+1e-5f);
      cparam[t]      = sc;
      cparam[CC+t]   = (dw_b[t]-bn1_m[t])*sc + bn1_b[t];
    }
    for (int i = t; i < 9*CC; i += 256){
      int k = i / CC, c = i - k*CC;
      dwt[i] = f2b(dw_w[c*9 + k]);
    }
  }
  int i = blockIdx.x*256 + t;
  if (i >= WALL_PAIRS) return;
  int e = i*2;
  float a, b;
  if (e < WQKV_ELEMS){ a = qkv_w[e]; b = qkv_w[e+1]; }
  else if (e < WQKV_ELEMS+WPROJ_ELEMS){ a = proj_w[e-WQKV_ELEMS]; b = proj_w[e-WQKV_ELEMS+1]; }
  else { a = si_w1[e-WQKV_ELEMS-WPROJ_ELEMS]; b = si_w1[e-WQKV_ELEMS-WPROJ_ELEMS+1]; }
  *(unsigned*)(void*)(wb + e) = cvt2(a, b);
}

// ---------------- K1: QKV GEMM via MFMA, whole B in LDS, 16-row waves ----------------
// Block 512 thr = 8 waves covering 128 rows; wave = 16 rows x 192 cols.
// acc[12]=48 regs + ~70 arch <= 128 total -> 2 blocks/CU (LDS 2x72KB=144KB fits).
__global__ __launch_bounds__(512, 4) void k_qkv(const float* __restrict__ x1, const float* __restrict__ x2,
                                                const ushortT* __restrict__ wb,
                                                ushortT* __restrict__ q1, ushortT* __restrict__ k2,
                                                ushortT* __restrict__ v1){
  __shared__ char Bs[CC*CC*2];     // 73728 B
  int z = blockIdx.y;
  const float* src = (z == 1) ? x2 : x1;
  ushortT* dst = (z == 0) ? q1 : ((z == 1) ? k2 : v1);
  stage_B512(wb + (size_t)z*CC*CC, Bs);

  int w = threadIdx.x >> 6, l = threadIdx.x & 63;
  int row0 = blockIdx.x*128 + w*16;
  int lr = l & 15;            // frag row (A) / col (B)
  int hk = l >> 4;            // k-phase
  f32x4 acc[12];
  #pragma unroll
  for (int n=0; n<12; n++) acc[n] = (f32x4){0.f,0.f,0.f,0.f};

  const float* ap = src + (size_t)(row0 + lr)*CC + hk*8;
  __syncthreads();

  #pragma unroll
  for (int ks = 0; ks < 6; ks++){
    float4 p0 = *(const float4*)(ap + ks*32);
    float4 p1 = *(const float4*)(ap + ks*32 + 4);
    ABu a;
    a.u[0] = cvt2(p0.x, p0.y); a.u[1] = cvt2(p0.z, p0.w);
    a.u[2] = cvt2(p1.x, p1.y); a.u[3] = cvt2(p1.z, p1.w);
    int kb = ks*64 + hk*16;
    #pragma unroll
    for (int n=0; n<12; n++){
      bf16x8 bfr = ldsB(Bs, n*16 + lr, kb);
      acc[n] = __builtin_amdgcn_mfma_f32_16x16x32_bf16(a.v, bfr, acc[n], 0, 0, 0);
    }
  }
  int crow = hk*4, ccol = lr;
  #pragma unroll
  for (int n=0; n<12; n++)
    #pragma unroll
    for (int r=0; r<4; r++){
      int m = row0 + crow + r;
      dst[(size_t)m*CC + n*16 + ccol] = f2b(acc[n][r]);
    }
}

// ---------------- K2: windowed attention (one branch per template) ----------------
template<int HSP, int WSP>
__global__ __launch_bounds__(256) void k_attn(const ushortT* __restrict__ q1, const ushortT* __restrict__ k2,
                                              const ushortT* __restrict__ v1, const float* __restrict__ pos,
                                              ushortT* __restrict__ att){
  constexpr int BR = (HSP == 4) ? 0 : 1;
  constexpr int NWH = HH / HSP, NWW = WW / WSP;
  constexpr int CH0 = BR * CBh;
  __shared__ float ks[64][CBh];
  __shared__ float vs[64][CBh];
  __shared__ float ps[RTAB*HBn];
  int t = threadIdx.x;
  int wid = blockIdx.x;
  int b = wid / (NWH*NWW);
  int rem = wid - b*(NWH*NWW);
  int hi = rem / NWW, wj = rem - hi*NWW;
  for (int i = t; i < RTAB*HBn; i += 256) ps[i] = pos[(size_t)BR*RTAB*HBn + i];
  #pragma unroll
  for (int r = 0; r < 3; r++){
    int idx = t + r*256;        // < 768 = 64 pix * 12 segs
    int pix = idx / 12, seg = idx - pix*12;
    int ii = pix / WSP, jj = pix - ii*WSP;
    size_t base = (((size_t)b*LL) + (size_t)(hi*HSP+ii)*WW + wj*WSP + jj)*CC + CH0 + seg*8;
    uint4 uk = *(const uint4*)(const void*)(k2 + base);
    unpack8(uk, &ks[pix][seg*8]);
    uint4 uv = *(const uint4*)(const void*)(v1 + base);
    unpack8(uv, &vs[pix][seg*8]);
  }
  __syncthreads();
  int h = t >> 6, lane = t & 63;
  int i1 = lane / WSP, j1 = lane - i1*WSP;
  size_t lq = ((size_t)b*LL) + (size_t)(hi*HSP+i1)*WW + wj*WSP + j1;
  const ushortT* qrow = q1 + lq*CC + CH0 + h*HDd;
  float qf[HDd];
  #pragma unroll
  for (int d0 = 0; d0 < HDd; d0 += 8){
    uint4 u = *(const uint4*)(const void*)(qrow + d0);
    unpack8(u, &qf[d0]);
  }
  #pragma unroll
  for (int d=0; d<HDd; d++) qf[d] *= 0.20412414523193154f;   // 1/sqrt(24)
  float lg[64];
  #pragma unroll
  for (int m = 0; m < 64; m++){
    const float* kr = &ks[m][h*HDd];
    float s = 0.f;
    #pragma unroll
    for (int d=0; d<HDd; d++) s = fmaf(qf[d], kr[d], s);
    int i2 = m / WSP, j2 = m - i2*WSP;
    int ridx = (i1-i2+HSP-1)*(2*WSP-1) + (j1-j2+WSP-1);
    lg[m] = s + ps[ridx*HBn + h];
  }
  float mx = lg[0];
  #pragma unroll
  for (int m=1;m<64;m++) mx = fmaxf(mx, lg[m]);
  float sum = 0.f;
  #pragma unroll
  for (int m=0;m<64;m++){ lg[m] = __expf(lg[m]-mx); sum += lg[m]; }
  float inv = 1.0f / sum;
  float z[HDd];
  #pragma unroll
  for (int d=0;d<HDd;d++) z[d] = 0.f;
  #pragma unroll
  for (int m=0;m<64;m++){
    float p = lg[m]*inv;
    const float* vr = &vs[m][h*HDd];
    #pragma unroll
    for (int d=0;d<HDd;d++) z[d] = fmaf(p, vr[d], z[d]);
  }
  ushortT* orow = att + lq*CC + CH0 + h*HDd;
  #pragma unroll
  for (int d0=0; d0<HDd; d0+=8){
    uint4 u;
    u.x = pack2(z[d0+0], z[d0+1]);
    u.y = pack2(z[d0+2], z[d0+3]);
    u.z = pack2(z[d0+4], z[d0+5]);
    u.w = pack2(z[d0+6], z[d0+7]);
    *(uint4*)(void*)(orow + d0) = u;
  }
}

// ---------------- K3: depthwise 3x3 conv + BN + GELU, 8 channels/thread ----------------
__global__ __launch_bounds__(256) void k_conv(const ushortT* __restrict__ v1,
                                              const ushortT* __restrict__ dwt,
                                              const float* __restrict__ cparam,
                                              ushortT* __restrict__ cx){
  int tid = blockIdx.x*256 + threadIdx.x;     // SZ/8 total
  int grp = tid % 24;
  int pix = tid / 24;
  int j = pix & (WW-1);
  int rest = pix >> 7;
  int i = rest & (HH-1);
  int b = rest >> 7;
  int c0 = grp*8;
  uint4 wreg[9];
  #pragma unroll
  for (int k=0;k<9;k++) wreg[k] = *(const uint4*)(const void*)(dwt + k*CC + c0);
  float acc[8];
  #pragma unroll
  for (int t2=0;t2<8;t2++) acc[t2]=0.f;
  #pragma unroll
  for (int ki=0;ki<3;ki++){
    int ii = i + ki - 1;
    if (ii < 0 || ii >= HH) continue;
    #pragma unroll
    for (int kj=0;kj<3;kj++){
      int jj = j + kj - 1;
      if (jj < 0 || jj >= WW) continue;
      uint4 uv = *(const uint4*)(const void*)(v1 + (((size_t)b*LL) + (size_t)ii*WW + jj)*CC + c0);
      float fv[8], fw[8];
      unpack8(uv, fv);
      unpack8(wreg[ki*3+kj], fw);
      #pragma unroll
      for (int t2=0;t2<8;t2++) acc[t2] = fmaf(fv[t2], fw[t2], acc[t2]);
    }
  }
  float4 s0 = *(const float4*)(cparam + c0);
  float4 s1 = *(const float4*)(cparam + c0 + 4);
  float4 o0 = *(const float4*)(cparam + CC + c0);
  float4 o1 = *(const float4*)(cparam + CC + c0 + 4);
  float scv[8] = {s0.x,s0.y,s0.z,s0.w,s1.x,s1.y,s1.z,s1.w};
  float ofv[8] = {o0.x,o0.y,o0.z,o0.w,o1.x,o1.y,o1.z,o1.w};
  unsigned ou[4];
  #pragma unroll
  for (int t2=0;t2<4;t2++){
    float y0 = gelu_exact(acc[2*t2]  *scv[2*t2]   + ofv[2*t2]);
    float y1 = gelu_exact(acc[2*t2+1]*scv[2*t2+1] + ofv[2*t2+1]);
    ou[t2] = pack2(y0, y1);
  }
  uint4 res; res.x=ou[0]; res.y=ou[1]; res.z=ou[2]; res.w=ou[3];
  *(uint4*)(void*)(cx + (size_t)pix*CC + c0) = res;
}

// ---------------- K4: per-pixel SE gate via MFMA ----------------
__global__ __launch_bounds__(256) void k_gate(const ushortT* __restrict__ att,
                                              const ushortT* __restrict__ wsi,
                                              const float* __restrict__ gparam,
                                              const float* __restrict__ si_b2,
                                              float* __restrict__ gate){
  int w = threadIdx.x >> 6, l = threadIdx.x & 63;
  int row0 = blockIdx.x*128 + w*32;
  int lr = l & 15;
  int lk = (l >> 4) * 8;
  f32x4 acc[2][6];
  #pragma unroll
  for (int rt=0; rt<2; rt++)
    #pragma unroll
    for (int n=0; n<6; n++) acc[rt][n] = (f32x4){0.f,0.f,0.f,0.f};
  #pragma unroll
  for (int ks = 0; ks < 6; ks++){
    int k0 = ks*32 + lk;
    bf16x8 a0 = *(const bf16x8*)(const void*)(att + (size_t)(row0 + lr)*CC + k0);
    bf16x8 a1 = *(const bf16x8*)(const void*)(att + (size_t)(row0 + 16 + lr)*CC + k0);
    #pragma unroll
    for (int n=0; n<6; n++){
      bf16x8 bfr = *(const bf16x8*)(const void*)(wsi + (size_t)(n*16 + lr)*CC + k0);
      acc[0][n] = __builtin_amdgcn_mfma_f32_16x16x32_bf16(a0, bfr, acc[0][n], 0, 0, 0);
      acc[1][n] = __builtin_amdgcn_mfma_f32_16x16x32_bf16(a1, bfr, acc[1][n], 0, 0, 0);
    }
  }
  int crow = (l >> 4) * 4, ccol = l & 15;
  float sc6[6], cb6[6], w26[6];
  #pragma unroll
  for (int n=0; n<6; n++){
    int o = n*16 + ccol;
    sc6[n] = gparam[o];
    cb6[n] = gparam[CBh + o];
    w26[n] = gparam[2*CBh + o];
  }
  float sb2 = si_b2[0];
  float ps[2][4];
  #pragma unroll
  for (int rt=0; rt<2; rt++)
    #pragma unroll
    for (int r=0; r<4; r++) ps[rt][r] = 0.f;
  #pragma unroll
  for (int rt=0; rt<2; rt++)
    #pragma unroll
    for (int n=0; n<6; n++)
      #pragma unroll
      for (int r=0; r<4; r++){
        float x = acc[rt][n][r]*sc6[n] + cb6[n];
        ps[rt][r] += gelu_exact(x) * w26[n];
      }
  #pragma unroll
  for (int rt=0; rt<2; rt++)
    #pragma unroll
    for (int r=0; r<4; r++){
      float v = ps[rt][r];
      #pragma unroll
      for (int off = 1; off < 16; off <<= 1) v += __shfl_xor(v, off, 64);
      ps[rt][r] = v;
    }
  if (ccol == 0){
    #pragma unroll
    for (int rt=0; rt<2; rt++)
      #pragma unroll
      for (int r=0; r<4; r++){
        int m = row0 + rt*16 + crow + r;
        gate[m] = 1.0f / (1.0f + __expf(-(ps[rt][r] + sb2)));
      }
  }
}

// ---------------- K5: proj GEMM via MFMA, whole B in LDS, 16-row waves, fused gate ----------------
__global__ __launch_bounds__(512, 4) void k_proj(const ushortT* __restrict__ att, const ushortT* __restrict__ cx,
                                                 const float* __restrict__ gate,
                                                 const ushortT* __restrict__ wp, const float* __restrict__ pbias,
                                                 float* __restrict__ out){
  __shared__ char Bs[CC*CC*2];     // 73728 B
  stage_B512(wp, Bs);

  int w = threadIdx.x >> 6, l = threadIdx.x & 63;
  int row0 = blockIdx.x*128 + w*16;
  int lr = l & 15;
  int hk = l >> 4;
  float gv = gate[row0 + lr];
  f32x4 acc[12];
  #pragma unroll
  for (int n=0; n<12; n++) acc[n] = (f32x4){0.f,0.f,0.f,0.f};

  size_t base = (size_t)(row0 + lr)*CC + hk*8;
  __syncthreads();

  #pragma unroll
  for (int ks = 0; ks < 6; ks++){
    uint4 ua = *(const uint4*)(const void*)(att + base + ks*32);
    uint4 uc = *(const uint4*)(const void*)(cx  + base + ks*32);
    float fa[8], fc[8];
    unpack8(ua, fa); unpack8(uc, fc);
    #pragma unroll
    for (int j=0;j<8;j++) fa[j] = fmaf(gv, fc[j], fa[j]);
    ABu a;
    a.u[0] = cvt2(fa[0], fa[1]); a.u[1] = cvt2(fa[2], fa[3]);
    a.u[2] = cvt2(fa[4], fa[5]); a.u[3] = cvt2(fa[6], fa[7]);
    int kb = ks*64 + hk*16;
    #pragma unroll
    for (int n=0; n<12; n++){
      bf16x8 bfr = ldsB(Bs, n*16 + lr, kb);
      acc[n] = __builtin_amdgcn_mfma_f32_16x16x32_bf16(a.v, bfr, acc[n], 0, 0, 0);
    }
  }
  int crow = hk*4, ccol = lr;
  #pragma unroll
  for (int n=0; n<12; n++){
    float bv = pbias[n*16 + ccol];
    #pragma unroll
    for (int r=0; r<4; r++){
      int m = row0 + crow + r;
      out[(size_t)m*CC + n*16 + ccol] = acc[n][r] + bv;
    }
  }
}

extern "C" void kernel_launch(void* const* d_in, const int* in_sizes, int n_in,
                              void* d_out, int out_size, void* d_ws, size_t ws_size,
                              hipStream_t stream){
  const float* x1    = (const float*)d_in[0];
  const float* x2    = (const float*)d_in[1];
  const float* qkv_w = (const float*)d_in[2];
  const float* proj_w= (const float*)d_in[3];
  const float* proj_b= (const float*)d_in[4];
  const float* pw    = (const float*)d_in[5];
  const float* pb    = (const float*)d_in[6];
  const float* g1    = (const float*)d_in[7];
  const float* b1    = (const float*)d_in[8];
  const float* w1    = (const float*)d_in[9];
  const float* c1    = (const float*)d_in[10];
  const float* g2    = (const float*)d_in[11];
  const float* b2    = (const float*)d_in[12];
  const float* w2    = (const float*)d_in[13];
  const float* c2    = (const float*)d_in[14];
  const float* g3    = (const float*)d_in[15];
  const float* b3    = (const float*)d_in[16];
  const float* w3    = (const float*)d_in[17];
  const float* c3    = (const float*)d_in[18];
  const float* dw_w  = (const float*)d_in[19];
  const float* dw_b  = (const float*)d_in[20];
  const float* bn1_g = (const float*)d_in[21];
  const float* bn1_b = (const float*)d_in[22];
  const float* bn1_m = (const float*)d_in[23];
  const float* bn1_v = (const float*)d_in[24];
  const float* si_w1 = (const float*)d_in[25];
  const float* si_b1 = (const float*)d_in[26];
  const float* bn2_g = (const float*)d_in[27];
  const float* bn2_b = (const float*)d_in[28];
  const float* bn2_m = (const float*)d_in[29];
  const float* bn2_v = (const float*)d_in[30];
  const float* si_w2 = (const float*)d_in[31];
  const float* si_b2 = (const float*)d_in[32];
  float* out = (float*)d_out;

  char* ws = (char*)d_ws;
  const size_t SZ  = (size_t)BDIM * LL * CC;   // 25,165,824 elements
  const size_t SZB = SZ * 2;                   // bf16 bytes per buffer
  ushortT* q1   = (ushortT*)(ws);
  ushortT* v1   = (ushortT*)(ws + SZB);
  ushortT* k2   = (ushortT*)(ws + 2*SZB);
  ushortT* att  = (ushortT*)(ws + 3*SZB);
  float*   gate = (float*)  (ws + 4*SZB);
  float*   pos  = (float*)  (ws + 4*SZB + (size_t)BDIM*LL*sizeof(float));
  ushortT* wbf  = (ushortT*)(ws + 4*SZB + (size_t)BDIM*LL*sizeof(float) + 16384);
  ushortT* wproj = wbf + WQKV_ELEMS;
  ushortT* wsi   = wproj + WPROJ_ELEMS;
  float*   gparam = (float*)(wbf + WQKV_ELEMS + WPROJ_ELEMS + WSI_ELEMS);
  float*   cparam = gparam + 3*CBh;
  ushortT* dwt    = (ushortT*)(cparam + 2*CC);
  ushortT* convx = q1;   // q1 dead after attention

  k_pos<<<dim3(2), dim3(256), 0, stream>>>(pw,pb,g1,b1,w1,c1,g2,b2,w2,c2,g3,b3,w3,c3,pos);
  k_cvtw<<<dim3((WALL_PAIRS+255)/256), dim3(256), 0, stream>>>(qkv_w, proj_w, si_w1,
      si_b1, bn2_g, bn2_b, bn2_m, bn2_v, si_w2,
      dw_w, dw_b, bn1_g, bn1_b, bn1_m, bn1_v, wbf, gparam, cparam, dwt);
  k_qkv<<<dim3(1024,3), dim3(512), 0, stream>>>(x1, x2, wbf, q1, k2, v1);
  k_attn<4,16><<<dim3(2048), dim3(256), 0, stream>>>(q1, k2, v1, pos, att);
  k_attn<16,4><<<dim3(2048), dim3(256), 0, stream>>>(q1, k2, v1, pos, att);
  k_conv<<<dim3((unsigned)(SZ/8/256)), dim3(256), 0, stream>>>(v1, dwt, cparam, convx);
  k_gate<<<dim3(1024), dim3(256), 0, stream>>>(att, wsi, gparam, si_b2, gate);
  k_proj<<<dim3(1024), dim3(512), 0, stream>>>(att, convx, gate, wproj, proj_b, out);
}